// Round 7
// baseline (29835.565 us; speedup 1.0000x reference)
//
#include <hip/hip_runtime.h>
#include <hip/hip_bf16.h>
#include <stdint.h>

// ESN: out[t] = tanh(U[t] + W_res @ s_{t-1}), T=16384 sequential steps.
// Kernel 1: U = X@W_in^T into d_out in place.
// Kernel 2: 64 blocks x ONE WAVE (64 lanes), 16 rows/block, 4 lanes/row.
// r6 lesson: poll mechanism latency is fixed (~LLC RT) regardless of scope
// tricks; the win is structural — single-wave blocks kill the 16-wave
// barrier and spread the LDS gather over 64 CUs' LDS pipes.
// Exchange (r5/r6-proven): 4B packets (24-bit value | 8-bit tag), agent-scope
// stores/loads, depth-2 ping-pong, equality tag check. Lane L polls 16 slots
// {k*64+L} (coalesced), stages them to LDS, gathers its rows' nnz from LDS.

constexpr int T_N = 16384;
constexpr int R_N = 1024;
constexpr int I_N = 128;

// ---------------------------------------------------------------- kernel 1
constexpr int BT = 64, BR = 64;

__global__ __launch_bounds__(256) void gemm_u_kernel(
    const float* __restrict__ X, const float* __restrict__ Win,
    float* __restrict__ U)
{
    __shared__ float XS[BT][68];
    __shared__ float WS[BR][68];
    const int tid = threadIdx.x;
    const int ty = tid >> 4, tx = tid & 15;
    const int t0 = blockIdx.x * BT;
    const int r0 = blockIdx.y * BR;
    float acc[4][4] = {};

    for (int k0 = 0; k0 < I_N; k0 += 64) {
        for (int idx = tid; idx < BT * 16; idx += 256) {
            int row = idx >> 4, c4 = (idx & 15) << 2;
            *reinterpret_cast<float4*>(&XS[row][c4]) =
                *reinterpret_cast<const float4*>(&X[(size_t)(t0 + row) * I_N + k0 + c4]);
        }
        for (int idx = tid; idx < BR * 16; idx += 256) {
            int row = idx >> 4, c4 = (idx & 15) << 2;
            *reinterpret_cast<float4*>(&WS[row][c4]) =
                *reinterpret_cast<const float4*>(&Win[(size_t)(r0 + row) * I_N + k0 + c4]);
        }
        __syncthreads();
#pragma unroll
        for (int k = 0; k < 64; k += 4) {
            float4 a[4], b[4];
#pragma unroll
            for (int i = 0; i < 4; ++i)
                a[i] = *reinterpret_cast<const float4*>(&XS[ty + 16 * i][k]);
#pragma unroll
            for (int jj = 0; jj < 4; ++jj)
                b[jj] = *reinterpret_cast<const float4*>(&WS[tx + 16 * jj][k]);
#pragma unroll
            for (int i = 0; i < 4; ++i)
#pragma unroll
                for (int jj = 0; jj < 4; ++jj)
                    acc[i][jj] += a[i].x * b[jj].x + a[i].y * b[jj].y +
                                  a[i].z * b[jj].z + a[i].w * b[jj].w;
        }
        __syncthreads();
    }
#pragma unroll
    for (int i = 0; i < 4; ++i)
#pragma unroll
        for (int jj = 0; jj < 4; ++jj)
            U[(size_t)(t0 + ty + 16 * i) * R_N + (r0 + tx + 16 * jj)] = acc[i][jj];
}

// ---------------------------------------------------------------- kernel 2
constexpr int GBLK = 64;              // blocks, one wave each (<=256 CUs)
constexpr int B2   = 64;              // one wave
constexpr int RPB  = R_N / GBLK;      // 16 rows per block
constexpr int TPR  = 4;               // lanes per row
constexpr int KMAX = 96;              // nnz/row cap (validated r1..r6)
constexpr int NSL  = KMAX / TPR;      // 24 register slots per lane
constexpr int SPL  = R_N / B2;        // 16 poll slots per lane
constexpr int PCAP = 1 << 20;         // anti-hang poll cap

__device__ __forceinline__ float fast_tanh(float x) {
    float ax = fabsf(x);
    float e  = __expf(-2.0f * ax);
    float y  = (1.0f - e) / (1.0f + e);
    return copysignf(y, x);
}

__global__ __launch_bounds__(64) void esn_scan_kernel(
    const float* __restrict__ Wres, const float* __restrict__ state0,
    float* out, uint32_t* slots)
{
    __shared__ float sbuf[2][R_N];        // 8 KB ping-pong state
    __shared__ uint2 ell[RPB][KMAX];      // 12 KB (col, val-bits)
    __shared__ int   cnt[RPB];

    const int tid  = threadIdx.x;         // 0..63 (lane id)
    const int b    = blockIdx.x;
    const int row0 = b * RPB;

    // ---- one-time: extract this block's 16 sparse rows (float4 scan)
    if (tid < RPB) cnt[tid] = 0;
    __syncthreads();
    for (int idx = tid; idx < RPB * (R_N / 4); idx += B2) {
        int r = idx >> 8;                 // 256 float4 per row
        int c = (idx & 255) << 2;
        float4 w4 = *reinterpret_cast<const float4*>(
            &Wres[(size_t)(row0 + r) * R_N + c]);
        float wv[4] = {w4.x, w4.y, w4.z, w4.w};
#pragma unroll
        for (int e = 0; e < 4; ++e) {
            if (wv[e] != 0.0f) {
                int slot = atomicAdd(&cnt[r], 1);
                if (slot < KMAX)
                    ell[r][slot] = make_uint2((uint32_t)(c + e), __float_as_uint(wv[e]));
            }
        }
    }
    __syncthreads();

    // ---- hoist my slots into registers; per-lane real count kcnt
    const int rloc = tid >> 2;            // 0..15
    const int j    = tid & 3;             // 0..3
    const int row  = row0 + rloc;
    int   cols[NSL];
    float vals[NSL];
    int   kcnt;
    {
        int myn = cnt[rloc];
        if (myn > KMAX) myn = KMAX;
        kcnt = (myn > j) ? (((myn - 1 - j) >> 2) + 1) : 0;
#pragma unroll
        for (int k = 0; k < NSL; ++k) {
            int slot = j + (k << 2);
            if (slot < myn) {
                uint2 e = ell[rloc][slot];
                cols[k] = (int)e.x;
                vals[k] = __uint_as_float(e.y);
            } else { cols[k] = 0; vals[k] = 0.0f; }
        }
    }

    // seed parity 1 (= (0-1)&1) with state0; coalesced
#pragma unroll
    for (int k = 0; k < SPL; ++k) sbuf[1][(k << 6) + tid] = state0[(k << 6) + tid];
    float u_cur = (j == 0) ? out[row] : 0.0f;
    __syncthreads();

    // ---- sequential scan (single wave: barriers are cheap waitcnts)
    for (int t = 0; t < T_N; ++t) {
        const int p = (t - 1) & 1;        // parity holding s_{t-1}

        float u_next = 0.0f;              // prefetch next u (same-lane slot)
        if (j == 0 && t + 1 < T_N) u_next = out[(size_t)(t + 1) * R_N + row];

        if (t > 0) {
            const uint32_t* base = slots + ((size_t)p << 10);
            const uint32_t want8 = (uint32_t)t & 0xFFu;   // s_{t-1} tag
            uint32_t w[SPL];
            int sp = 0;
            bool fresh = false;
            do {
#pragma unroll
                for (int k = 0; k < SPL; ++k)
                    w[k] = __hip_atomic_load(base + (k << 6) + tid,
                                             __ATOMIC_RELAXED,
                                             __HIP_MEMORY_SCOPE_AGENT);
                uint32_t bad = 0;
#pragma unroll
                for (int k = 0; k < SPL; ++k) bad |= (w[k] ^ want8);
                fresh = ((bad & 0xFFu) == 0u);
            } while (!fresh && ++sp < PCAP);
#pragma unroll
            for (int k = 0; k < SPL; ++k)
                sbuf[p][(k << 6) + tid] = __uint_as_float(w[k] & 0xFFFFFF00u);
        }
        __syncthreads();                  // single-wave: ~free

        float acc = 0.0f;
#pragma unroll
        for (int k = 0; k < NSL; ++k)
            if (k < kcnt) acc += vals[k] * sbuf[p][cols[k]];

        acc += __shfl_xor(acc, 1, TPR);
        acc += __shfl_xor(acc, 2, TPR);

        if (j == 0) {
            float y = fast_tanh(u_cur + acc);
            uint32_t bits = __float_as_uint(y);
            uint32_t pkt  = ((bits + 0x80u) & 0xFFFFFF00u)   // round to 24b
                          | ((uint32_t)(t + 1) & 0xFFu);
            // publish FIRST (16 lanes -> one 64B coalesced agent store)
            __hip_atomic_store(&slots[((size_t)(t & 1) << 10) + row], pkt,
                               __ATOMIC_RELAXED, __HIP_MEMORY_SCOPE_AGENT);
            out[(size_t)t * R_N + row] = y;
        }
        u_cur = u_next;
        // depth-2 safety: this parity is rewritten at t+2 only after the
        // writer passed step t+1, which required every block's tag-(t+1)
        // publish, which follows every step-t gather. Max lead = 1 step.
    }
}

// ---------------------------------------------------------------- launcher
extern "C" void kernel_launch(void* const* d_in, const int* in_sizes, int n_in,
                              void* d_out, int out_size, void* d_ws, size_t ws_size,
                              hipStream_t stream)
{
    const float* X      = (const float*)d_in[0];   // (T, I)
    const float* W_in   = (const float*)d_in[1];   // (R, I)
    const float* W_res  = (const float*)d_in[2];   // (R, R)
    const float* state0 = (const float*)d_in[3];   // (R,)
    float* out = (float*)d_out;                    // (T, R)
    uint32_t* slots = (uint32_t*)d_ws;             // 2 x 1024 x 4B packets

    // tags must differ from any wanted tag at start (memset 0: tag 0, first
    // wanted tag is 1; t=256 wrap-around safe per monotone-overwrite argument)
    hipMemsetAsync(d_ws, 0, (size_t)2 * R_N * sizeof(uint32_t), stream);

    dim3 g1(T_N / BT, R_N / BR);
    gemm_u_kernel<<<g1, 256, 0, stream>>>(X, W_in, out);

    esn_scan_kernel<<<GBLK, B2, 0, stream>>>(W_res, state0, out, slots);
}